// Round 7
// baseline (1106.408 us; speedup 1.0000x reference)
//
#include <hip/hip_runtime.h>
#include <hip/hip_cooperative_groups.h>

typedef unsigned long long u64;
#define V0TOK 32000
#define EDIM  1024

__device__ __forceinline__ float dot4(float4 a, float4 b) {
    return fmaf(a.x, b.x, fmaf(a.y, b.y, fmaf(a.z, b.z, a.w * b.w)));
}

// ---------------------------------------------------------------------------
// Cooperative RNN: 128 blocks x 512 threads. Block b owns h rows j=8b+w.
// R3/R5/R6 data: each agent-scope fabric op costs ~1.5-2.5us under poll
// contention, scaling with total poll traffic. Fix: XCD-hierarchical fanout.
//   producers: tagged {t+1,val} u64 relaxed agent stores to hbuf (L3), as R6.
//   leaders (b<8, ~one per XCD under RR dispatch): poll hbuf own-slots (only
//     8 blocks on fabric now), then mirror the tagged u64s into stg[xcc] with
//     PLAIN stores -> land in the leader's XCD L2 (coherent within XCD).
//   followers: poll their 2 slots of stg[my_xcc] with VOLATILE loads (sc0,
//     L2-local, no fabric traffic, ~250cy). Tags self-certify per slot.
//   safety: every block pre-clears stg[its own xcc] (clearer-set >= reader-
//     set -> no stale tags for ANY dispatch mapping); follower poll is
//     BOUNDED with sticky fallback to authoritative hbuf (no hang, no silent
//     staleness -- worst case degrades to R6 perf).
// ---------------------------------------------------------------------------
__global__ __launch_bounds__(512, 1) void k_rnn(
    const int* __restrict__ diag, const int* __restrict__ proc,
    const int* __restrict__ med,  const int* __restrict__ dtok,
    const float* __restrict__ enc, const float* __restrict__ dec,
    const float* __restrict__ attw,
    const float* __restrict__ wih, const float* __restrict__ whh,
    const float* __restrict__ bih, const float* __restrict__ bhh,
    float* __restrict__ ctx_ws, float* __restrict__ c_ws,
    u64* __restrict__ hbuf, float* __restrict__ hrelu,
    u64* __restrict__ stg)
{
    const int b = blockIdx.x, tid = threadIdx.x;
    const int w = tid >> 6, l = tid & 63;

    unsigned xcc;
    asm("s_getreg_b32 %0, hwreg(HW_REG_XCC_ID)" : "=s"(xcc));
    xcc &= 7;
    u64* stg_x = stg + (size_t)xcc * 2048;       // [2 parities][1024] tagged u64
    const bool lead = (b < 8);

    __shared__ float Wx[24 * 1024];     // 96KB: W_ih x-half, row (g*8+w)
    __shared__ float sm[320];
    __shared__ float red1[8], red2[8];
    __shared__ float hlds[1024];

    // ---- Phase A: clear hbuf (blocks 0-3, agent) + clear own XCD's stg
    // (ALL resident blocks, plain stores -> own L2; duplicate zeros benign)
    // + ctx scores (blocks <40) ----
    if (b < 4)
        __hip_atomic_store(&hbuf[b * 512 + tid], 0ull,
                           __ATOMIC_RELAXED, __HIP_MEMORY_SCOPE_AGENT);
    #pragma unroll
    for (int m = 0; m < 4; m++) stg_x[tid + 512 * m] = 0ull;
    if (b < 40) {
        int i = 8*b + w;   // 0..319
        int ridx = (i < 128) ? diag[i] : (i < 192 ? proc[i-128] : med[i-192]);
        const float4* row = (const float4*)(enc + (size_t)ridx * EDIM);
        const float4* we  = (const float4*)(attw + EDIM);   // w_e = attn_w[0,E:]
        float p = 0.f;
        #pragma unroll
        for (int m = 0; m < 4; m++) p += dot4(row[l + 64*m], we[l + 64*m]);
        #pragma unroll
        for (int off = 32; off; off >>= 1) p += __shfl_xor(p, off);
        if (l == 0) ctx_ws[i] = p;
    }
    __threadfence();
    cooperative_groups::this_grid().sync();
    __threadfence();

    // ---- Phase B: per-block softmax (redundant) + c slice ----
    {
        float s1 = (tid < 320) ? ctx_ws[tid] : -1e30f;
        float mx = s1;
        #pragma unroll
        for (int off = 32; off; off >>= 1) mx = fmaxf(mx, __shfl_xor(mx, off));
        if (l == 0) red1[w] = mx;
        __syncthreads();
        mx = red1[0];
        #pragma unroll
        for (int k = 1; k < 8; k++) mx = fmaxf(mx, red1[k]);
        float e1 = (tid < 320) ? expf(s1 - mx) : 0.f;
        float ss = e1;
        #pragma unroll
        for (int off = 32; off; off >>= 1) ss += __shfl_xor(ss, off);
        if (l == 0) red2[w] = ss;
        __syncthreads();
        float tot = red2[0];
        #pragma unroll
        for (int k = 1; k < 8; k++) tot += red2[k];
        if (tid < 320) sm[tid] = e1 / tot;
        __syncthreads();

        int e = 8*b + w;
        float p = 0.f;
        for (int i = l; i < 320; i += 64) {
            int ridx = (i < 128) ? diag[i] : (i < 192 ? proc[i-128] : med[i-192]);
            p += sm[i] * enc[(size_t)ridx * EDIM + e];
        }
        #pragma unroll
        for (int off = 32; off; off >>= 1) p += __shfl_xor(p, off);
        if (l == 0) c_ws[e] = p;
    }
    __threadfence();
    cooperative_groups::this_grid().sync();
    __threadfence();

    // ---- Phase C ----
    const int jr = 8*b + w, jz = 1024 + jr, jn = 2048 + jr;

    // W_ih x-half rows -> LDS
    {
        const float4* s_r = (const float4*)(wih + (size_t)jr * 2048 + 1024);
        const float4* s_z = (const float4*)(wih + (size_t)jz * 2048 + 1024);
        const float4* s_n = (const float4*)(wih + (size_t)jn * 2048 + 1024);
        float4* d_r = (float4*)(Wx + (0*8 + w) * 1024);
        float4* d_z = (float4*)(Wx + (1*8 + w) * 1024);
        float4* d_n = (float4*)(Wx + (2*8 + w) * 1024);
        #pragma unroll
        for (int m = 0; m < 4; m++) {
            d_r[l + 64*m] = s_r[l + 64*m];
            d_z[l + 64*m] = s_z[l + 64*m];
            d_n[l + 64*m] = s_n[l + 64*m];
        }
    }

    // W_hh rows -> VGPRs
    float4 whr[4], whz[4], whn[4];
    {
        const float4* qr = (const float4*)(whh + (size_t)jr * 1024);
        const float4* qz = (const float4*)(whh + (size_t)jz * 1024);
        const float4* qn = (const float4*)(whh + (size_t)jn * 1024);
        #pragma unroll
        for (int m = 0; m < 4; m++) { whr[m] = qr[l + 64*m]; whz[m] = qz[l + 64*m]; whn[m] = qn[l + 64*m]; }
    }

    float4 c4[4], h4[4];
    {
        const float4* cp = (const float4*)c_ws;
        const float4* hp = (const float4*)(dec + (size_t)V0TOK * EDIM);  // h0 = x_0
        #pragma unroll
        for (int m = 0; m < 4; m++) { c4[m] = cp[l + 64*m]; h4[m] = hp[l + 64*m]; }
    }
    const float b_r  = bih[jr] + bhh[jr];
    const float b_z  = bih[jz] + bhh[jz];
    const float b_ni = bih[jn];
    const float b_nh = bhh[jn];

    float gic_r = 0.f, gic_z = 0.f, gic_n = 0.f;
    {
        const float4* pr = (const float4*)(wih + (size_t)jr * 2048);
        const float4* pz = (const float4*)(wih + (size_t)jz * 2048);
        const float4* pn = (const float4*)(wih + (size_t)jn * 2048);
        #pragma unroll
        for (int m = 0; m < 4; m++) {
            gic_r += dot4(pr[l + 64*m], c4[m]);
            gic_z += dot4(pz[l + 64*m], c4[m]);
            gic_n += dot4(pn[l + 64*m], c4[m]);
        }
    }

    __syncthreads();   // Wx staged

    const float4* WxR = (const float4*)(Wx + (0*8 + w) * 1024);
    const float4* WxZ = (const float4*)(Wx + (1*8 + w) * 1024);
    const float4* WxN = (const float4*)(Wx + (2*8 + w) * 1024);

    int tokreg = dtok[l];

    // gx for t=0 (x_0 == h0)
    float gxr = gic_r, gxz = gic_z, gxn = gic_n;
    #pragma unroll
    for (int m = 0; m < 4; m++) {
        gxr += dot4(WxR[l + 64*m], h4[m]);
        gxz += dot4(WxZ[l + 64*m], h4[m]);
        gxn += dot4(WxN[l + 64*m], h4[m]);
    }
    float4 xv[4];
    {
        int tok1 = __shfl(tokreg, 0);
        const float4* xp = (const float4*)(dec + (size_t)tok1 * EDIM);
        #pragma unroll
        for (int m = 0; m < 4; m++) xv[m] = xp[l + 64*m];
    }

    // h[j] extraction constants (wave-uniform)
    const int jmi = jr >> 8, jli = (jr >> 2) & 63, jci = jr & 3;

    bool fb = false;   // sticky fallback (uniform across block)

    for (int t = 0; t < 65; t++) {
        float hr = 0.f, hz = 0.f, hn_ = 0.f;
        #pragma unroll
        for (int m = 0; m < 4; m++) {
            hr  += dot4(whr[m], h4[m]);
            hz  += dot4(whz[m], h4[m]);
            hn_ += dot4(whn[m], h4[m]);
        }
        float sr = gxr + hr, sz = gxz + hz, sni = gxn, snh = hn_;
        #pragma unroll
        for (int off = 32; off; off >>= 1) {
            sr  += __shfl_xor(sr, off);  sz  += __shfl_xor(sz, off);
            sni += __shfl_xor(sni, off); snh += __shfl_xor(snh, off);
        }
        float rg = 1.f / (1.f + expf(-(sr + b_r)));
        float zg = 1.f / (1.f + expf(-(sz + b_z)));
        float ng = tanhf(sni + b_ni + rg * (snh + b_nh));

        float4 hs = (jmi == 0) ? h4[0] : (jmi == 1) ? h4[1] : (jmi == 2) ? h4[2] : h4[3];
        float hv0 = (jci == 0) ? hs.x : (jci == 1) ? hs.y : (jci == 2) ? hs.z : hs.w;
        float hv = __shfl(hv0, jli);
        float hnew = (1.f - zg) * ng + zg * hv;

        if (t < 64) {
            const int par = (t + 1) & 1;
            const unsigned tag = (unsigned)(t + 1);
            if (l == 0) {
                hrelu[t * 1024 + jr] = fmaxf(hnew, 0.f);
                u64 pk = ((u64)tag << 32) | (u64)__float_as_uint(hnew);
                __hip_atomic_store(&hbuf[par * 1024 + jr], pk,
                                   __ATOMIC_RELAXED, __HIP_MEMORY_SCOPE_AGENT);
            }

            // ---- overlap: gx(t+1) + x prefetch while stores fly ----
            gxr = gic_r; gxz = gic_z; gxn = gic_n;
            #pragma unroll
            for (int m = 0; m < 4; m++) {
                gxr += dot4(WxR[l + 64*m], xv[m]);
                gxz += dot4(WxZ[l + 64*m], xv[m]);
                gxn += dot4(WxN[l + 64*m], xv[m]);
            }
            if (t < 63) {
                int tok = __shfl(tokreg, t + 1);
                const float4* xp = (const float4*)(dec + (size_t)tok * EDIM);
                #pragma unroll
                for (int m = 0; m < 4; m++) xv[m] = xp[l + 64*m];
            }

            u64 va, vb2;
            if (lead) {
                // ---- leader: poll hbuf (quiet fabric), mirror into stg[xcc] ----
                u64* hb = hbuf + par * 1024;
                while (1) {
                    va  = __hip_atomic_load(&hb[2*tid],     __ATOMIC_RELAXED, __HIP_MEMORY_SCOPE_AGENT);
                    vb2 = __hip_atomic_load(&hb[2*tid + 1], __ATOMIC_RELAXED, __HIP_MEMORY_SCOPE_AGENT);
                    if (((unsigned)(va >> 32) == tag) & ((unsigned)(vb2 >> 32) == tag)) break;
                }
                u64* sp = stg_x + (size_t)par * 1024;
                sp[2*tid]     = va;      // plain stores -> this XCD's L2
                sp[2*tid + 1] = vb2;
                __syncthreads();         // prev h4 reads done
            } else {
                // ---- follower: bounded L2-local poll, sticky fallback ----
                bool got = false;
                if (!fb) {
                    volatile const u64* sp = stg_x + (size_t)par * 1024;
                    for (int it = 0; it < 8192; ++it) {
                        va  = sp[2*tid];
                        vb2 = sp[2*tid + 1];
                        if (((unsigned)(va >> 32) == tag) & ((unsigned)(vb2 >> 32) == tag)) { got = true; break; }
                    }
                }
                int allgot = __syncthreads_and(got ? 1 : 0);   // barrier: prev h4 reads done
                if (!allgot) {
                    fb = true;
                    u64* hb = hbuf + par * 1024;
                    while (1) {
                        va  = __hip_atomic_load(&hb[2*tid],     __ATOMIC_RELAXED, __HIP_MEMORY_SCOPE_AGENT);
                        vb2 = __hip_atomic_load(&hb[2*tid + 1], __ATOMIC_RELAXED, __HIP_MEMORY_SCOPE_AGENT);
                        if (((unsigned)(va >> 32) == tag) & ((unsigned)(vb2 >> 32) == tag)) break;
                    }
                }
            }
            hlds[2*tid]     = __uint_as_float((unsigned)va);
            hlds[2*tid + 1] = __uint_as_float((unsigned)vb2);
            __syncthreads();
            #pragma unroll
            for (int m = 0; m < 4; m++) h4[m] = ((const float4*)hlds)[l + 64*m];
            // next iteration's first barrier guards hlds overwrite
        } else {
            if (l == 0) hrelu[64 * 1024 + jr] = fmaxf(hnew, 0.f);
        }
    }
}

// ---------------------------------------------------------------------------
// logits = out_w @ relu(H)^T + out_b.
// Block 256 thr, tile 16 v x 65 t. Thread (q=tid&15, vl=(tid>>4)&3, s=tid>>6):
// rows {v0+vl+4r, r<4}, t-quarter s (17/16/16/16), k-slice 4q per 64-chunk.
// One 16B LDS read feeds 64 FMAs (4x fewer ds_read_b128 than R6 -> was
// LDS-pipe bound at 133us). acc[4][17] static. H staged via reg double-buffer
// (T14). Reduce over q (16-lane shfl), LDS-stage output, coalesced store.
// ---------------------------------------------------------------------------
__global__ __launch_bounds__(256, 4) void k_logits(
    const float* __restrict__ wo, const float* __restrict__ bo,
    const float* __restrict__ hrelu, float* __restrict__ out)
{
    __shared__ float Hs[65 * 68];     // 17.7KB; reused as Os[65][17] at the end
    const int tid = threadIdx.x;
    const int q = tid & 15, vl = (tid >> 4) & 3, s = tid >> 6;
    const int v0 = blockIdx.x * 16;
    const int T0 = (s == 0) ? 0 : (1 + 16 * s);   // quarters: 17,16,16,16

    const float* wrow[4];
    #pragma unroll
    for (int r = 0; r < 4; r++) {
        int v = v0 + vl + 4*r;
        wrow[r] = wo + (size_t)((v < 32002) ? v : 32001) * 1024;
    }

    float acc[4][17];
    #pragma unroll
    for (int r = 0; r < 4; r++)
        #pragma unroll
        for (int ti = 0; ti < 17; ti++) acc[r][ti] = 0.f;

    // stage registers: 4 float4/thread + 1 extra for tid<16 (65*16 = 1040)
    float4 st0, st1, st2, st3, st4;
    #define ISSUE(kc_) do {                                                   \
        int base = (kc_) * 64;                                                \
        { int idx = tid;       st0 = *(const float4*)(hrelu + (idx>>4)*1024 + base + 4*(idx&15)); } \
        { int idx = tid + 256; st1 = *(const float4*)(hrelu + (idx>>4)*1024 + base + 4*(idx&15)); } \
        { int idx = tid + 512; st2 = *(const float4*)(hrelu + (idx>>4)*1024 + base + 4*(idx&15)); } \
        { int idx = tid + 768; st3 = *(const float4*)(hrelu + (idx>>4)*1024 + base + 4*(idx&15)); } \
        if (tid < 16) st4 = *(const float4*)(hrelu + 64*1024 + base + 4*tid); \
    } while (0)
    #define WRITE() do {                                                      \
        { int idx = tid;       *(float4*)(Hs + (idx>>4)*68 + 4*(idx&15)) = st0; } \
        { int idx = tid + 256; *(float4*)(Hs + (idx>>4)*68 + 4*(idx&15)) = st1; } \
        { int idx = tid + 512; *(float4*)(Hs + (idx>>4)*68 + 4*(idx&15)) = st2; } \
        { int idx = tid + 768; *(float4*)(Hs + (idx>>4)*68 + 4*(idx&15)) = st3; } \
        if (tid < 16) *(float4*)(Hs + 64*68 + 4*tid) = st4;                   \
    } while (0)

    ISSUE(0);

    for (int kc = 0; kc < 16; kc++) {
        WRITE();                       // consumes stage regs of kc
        __syncthreads();               // Hs(kc) ready
        if (kc < 15) ISSUE(kc + 1);    // next tile in flight during compute

        float4 wv[4];
        #pragma unroll
        for (int r = 0; r < 4; r++) wv[r] = *(const float4*)(wrow[r] + kc * 64 + 4*q);

        const float* hp = Hs + 4*q;
        #pragma unroll
        for (int ti = 0; ti < 17; ti++) {
            if ((ti < 16) | (s == 0)) {
                float4 h4 = *(const float4*)(hp + (T0 + ti) * 68);
                #pragma unroll
                for (int r = 0; r < 4; r++) {
                    acc[r][ti] = fmaf(wv[r].x, h4.x, acc[r][ti]);
                    acc[r][ti] = fmaf(wv[r].y, h4.y, acc[r][ti]);
                    acc[r][ti] = fmaf(wv[r].z, h4.z, acc[r][ti]);
                    acc[r][ti] = fmaf(wv[r].w, h4.w, acc[r][ti]);
                }
            }
        }
        __syncthreads();               // Hs consumed; next WRITE may proceed
    }

    // reduce over q (16-lane groups), stage Os[65][17], coalesced store
    float* Os = Hs;
    #pragma unroll
    for (int ti = 0; ti < 17; ti++) {
        if ((ti < 16) | (s == 0)) {
            #pragma unroll
            for (int r = 0; r < 4; r++) {
                float s_ = acc[r][ti];
                s_ += __shfl_xor(s_, 1);
                s_ += __shfl_xor(s_, 2);
                s_ += __shfl_xor(s_, 4);
                s_ += __shfl_xor(s_, 8);
                if (q == 0) Os[(T0 + ti) * 17 + vl + 4*r] = s_;
            }
        }
    }
    __syncthreads();
    for (int idx = tid; idx < 65 * 16; idx += 256) {
        int t = idx >> 4, c = idx & 15;
        int vv = v0 + c;
        if (vv < 32002) out[(size_t)t * 32002 + vv] = Os[t * 17 + c] + bo[vv];
    }
}

// ---------------------------------------------------------------------------
extern "C" void kernel_launch(void* const* d_in, const int* in_sizes, int n_in,
                              void* d_out, int out_size, void* d_ws, size_t ws_size,
                              hipStream_t stream) {
    const int*   diag = (const int*)d_in[0];
    const int*   proc = (const int*)d_in[1];
    const int*   med  = (const int*)d_in[2];
    const int*   dtok = (const int*)d_in[3];
    const float* enc  = (const float*)d_in[4];
    const float* dec  = (const float*)d_in[5];
    const float* attw = (const float*)d_in[6];
    // d_in[7] = attn_b: uniform shift, cancels in softmax -> unused
    const float* wih  = (const float*)d_in[8];
    const float* whh  = (const float*)d_in[9];
    const float* bih  = (const float*)d_in[10];
    const float* bhh  = (const float*)d_in[11];
    const float* wo   = (const float*)d_in[12];
    const float* bo   = (const float*)d_in[13];
    float* out = (float*)d_out;

    // ws: [0,1280) ctx | [2048,6144) c | [16384,32768) hbuf(2x1024 u64) |
    //     [32768,299008) hrelu | [299008,430080) stg[8][2][1024] u64
    float* ctx_ws = (float*)d_ws;
    float* c_ws   = (float*)((char*)d_ws + 2048);
    u64*   hbuf   = (u64*)  ((char*)d_ws + 16384);
    float* hrelu  = (float*)((char*)d_ws + 32768);
    u64*   stg    = (u64*)  ((char*)d_ws + 299008);

    void* args[] = { (void*)&diag, (void*)&proc, (void*)&med, (void*)&dtok,
                     (void*)&enc, (void*)&dec, (void*)&attw,
                     (void*)&wih, (void*)&whh, (void*)&bih, (void*)&bhh,
                     (void*)&ctx_ws, (void*)&c_ws, (void*)&hbuf, (void*)&hrelu,
                     (void*)&stg };
    hipLaunchCooperativeKernel((void*)k_rnn, dim3(128), dim3(512), args, 0, stream);

    k_logits<<<dim3(2001), dim3(256), 0, stream>>>(wo, bo, hrelu, out);
}

// Round 8
// 477.743 us; speedup vs baseline: 2.3159x; 2.3159x over previous
//
#include <hip/hip_runtime.h>
#include <hip/hip_cooperative_groups.h>

typedef unsigned long long u64;
#define V0TOK 32000
#define EDIM  1024

__device__ __forceinline__ float dot4(float4 a, float4 b) {
    return fmaf(a.x, b.x, fmaf(a.y, b.y, fmaf(a.z, b.z, a.w * b.w)));
}

// ---------------------------------------------------------------------------
// Cooperative RNN: 128 blocks x 512 threads. Block b owns h rows j=8b+w.
// W_hh in VGPRs, W_ih x-half in LDS, c-half folded into gic.
// h exchange: R6 tag-poll protocol + PRODUCER-SIDE 8x REPLICATION.
//   R3/R5/R6 established: poll cost ~ per-L3-line request queue depth
//   (R6: 16 slots/line x 128 polling blocks ~ 2048 req/line/round).
//   Producers store the tagged {t+1,val} u64 to 8 replicas (8 extra
//   fire-and-forget relaxed agent stores per wave -- no ordering ops, no
//   leader chain, unlike failed R7). Consumers poll ONLY replica XCC_ID:
//   per-line pressure /8. Correct for ANY block->XCD mapping (all replicas
//   identical; xcc only steers locality). Distance-2 causality unchanged:
//   P stores h(t+3) over parity p only after all blocks stored h(t+2),
//   which requires every block's poll(t+1) on parity p succeeded.
// ---------------------------------------------------------------------------
__global__ __launch_bounds__(512, 1) void k_rnn(
    const int* __restrict__ diag, const int* __restrict__ proc,
    const int* __restrict__ med,  const int* __restrict__ dtok,
    const float* __restrict__ enc, const float* __restrict__ dec,
    const float* __restrict__ attw,
    const float* __restrict__ wih, const float* __restrict__ whh,
    const float* __restrict__ bih, const float* __restrict__ bhh,
    float* __restrict__ ctx_ws, float* __restrict__ c_ws,
    u64* __restrict__ hbuf, float* __restrict__ hrelu)
{
    const int b = blockIdx.x, tid = threadIdx.x;
    const int w = tid >> 6, l = tid & 63;

    unsigned xcc;
    asm("s_getreg_b32 %0, hwreg(HW_REG_XCC_ID)" : "=s"(xcc));
    xcc &= 7;

    __shared__ float Wx[24 * 1024];     // 96KB: W_ih x-half, row (g*8+w)
    __shared__ float sm[320];
    __shared__ float red1[8], red2[8];
    __shared__ float hlds[1024];

    // ---- Phase A: clear ALL hbuf replicas (blocks 0-31: 32x512 = 16K u64)
    // + ctx scores (blocks <40) ----
    if (b < 32)
        __hip_atomic_store(&hbuf[b * 512 + tid], 0ull,
                           __ATOMIC_RELAXED, __HIP_MEMORY_SCOPE_AGENT);
    if (b < 40) {
        int i = 8*b + w;   // 0..319
        int ridx = (i < 128) ? diag[i] : (i < 192 ? proc[i-128] : med[i-192]);
        const float4* row = (const float4*)(enc + (size_t)ridx * EDIM);
        const float4* we  = (const float4*)(attw + EDIM);   // w_e = attn_w[0,E:]
        float p = 0.f;
        #pragma unroll
        for (int m = 0; m < 4; m++) p += dot4(row[l + 64*m], we[l + 64*m]);
        #pragma unroll
        for (int off = 32; off; off >>= 1) p += __shfl_xor(p, off);
        if (l == 0) ctx_ws[i] = p;
    }
    __threadfence();
    cooperative_groups::this_grid().sync();
    __threadfence();

    // ---- Phase B: per-block softmax (redundant) + c slice ----
    {
        float s1 = (tid < 320) ? ctx_ws[tid] : -1e30f;
        float mx = s1;
        #pragma unroll
        for (int off = 32; off; off >>= 1) mx = fmaxf(mx, __shfl_xor(mx, off));
        if (l == 0) red1[w] = mx;
        __syncthreads();
        mx = red1[0];
        #pragma unroll
        for (int k = 1; k < 8; k++) mx = fmaxf(mx, red1[k]);
        float e1 = (tid < 320) ? expf(s1 - mx) : 0.f;
        float ss = e1;
        #pragma unroll
        for (int off = 32; off; off >>= 1) ss += __shfl_xor(ss, off);
        if (l == 0) red2[w] = ss;
        __syncthreads();
        float tot = red2[0];
        #pragma unroll
        for (int k = 1; k < 8; k++) tot += red2[k];
        if (tid < 320) sm[tid] = e1 / tot;
        __syncthreads();

        int e = 8*b + w;
        float p = 0.f;
        for (int i = l; i < 320; i += 64) {
            int ridx = (i < 128) ? diag[i] : (i < 192 ? proc[i-128] : med[i-192]);
            p += sm[i] * enc[(size_t)ridx * EDIM + e];
        }
        #pragma unroll
        for (int off = 32; off; off >>= 1) p += __shfl_xor(p, off);
        if (l == 0) c_ws[e] = p;
    }
    __threadfence();
    cooperative_groups::this_grid().sync();
    __threadfence();

    // ---- Phase C ----
    const int jr = 8*b + w, jz = 1024 + jr, jn = 2048 + jr;

    // W_ih x-half rows -> LDS
    {
        const float4* s_r = (const float4*)(wih + (size_t)jr * 2048 + 1024);
        const float4* s_z = (const float4*)(wih + (size_t)jz * 2048 + 1024);
        const float4* s_n = (const float4*)(wih + (size_t)jn * 2048 + 1024);
        float4* d_r = (float4*)(Wx + (0*8 + w) * 1024);
        float4* d_z = (float4*)(Wx + (1*8 + w) * 1024);
        float4* d_n = (float4*)(Wx + (2*8 + w) * 1024);
        #pragma unroll
        for (int m = 0; m < 4; m++) {
            d_r[l + 64*m] = s_r[l + 64*m];
            d_z[l + 64*m] = s_z[l + 64*m];
            d_n[l + 64*m] = s_n[l + 64*m];
        }
    }

    // W_hh rows -> VGPRs
    float4 whr[4], whz[4], whn[4];
    {
        const float4* qr = (const float4*)(whh + (size_t)jr * 1024);
        const float4* qz = (const float4*)(whh + (size_t)jz * 1024);
        const float4* qn = (const float4*)(whh + (size_t)jn * 1024);
        #pragma unroll
        for (int m = 0; m < 4; m++) { whr[m] = qr[l + 64*m]; whz[m] = qz[l + 64*m]; whn[m] = qn[l + 64*m]; }
    }

    float4 c4[4], h4[4];
    {
        const float4* cp = (const float4*)c_ws;
        const float4* hp = (const float4*)(dec + (size_t)V0TOK * EDIM);  // h0 = x_0
        #pragma unroll
        for (int m = 0; m < 4; m++) { c4[m] = cp[l + 64*m]; h4[m] = hp[l + 64*m]; }
    }
    const float b_r  = bih[jr] + bhh[jr];
    const float b_z  = bih[jz] + bhh[jz];
    const float b_ni = bih[jn];
    const float b_nh = bhh[jn];

    float gic_r = 0.f, gic_z = 0.f, gic_n = 0.f;
    {
        const float4* pr = (const float4*)(wih + (size_t)jr * 2048);
        const float4* pz = (const float4*)(wih + (size_t)jz * 2048);
        const float4* pn = (const float4*)(wih + (size_t)jn * 2048);
        #pragma unroll
        for (int m = 0; m < 4; m++) {
            gic_r += dot4(pr[l + 64*m], c4[m]);
            gic_z += dot4(pz[l + 64*m], c4[m]);
            gic_n += dot4(pn[l + 64*m], c4[m]);
        }
    }

    __syncthreads();   // Wx staged

    const float4* WxR = (const float4*)(Wx + (0*8 + w) * 1024);
    const float4* WxZ = (const float4*)(Wx + (1*8 + w) * 1024);
    const float4* WxN = (const float4*)(Wx + (2*8 + w) * 1024);

    int tokreg = dtok[l];

    // gx for t=0 (x_0 == h0)
    float gxr = gic_r, gxz = gic_z, gxn = gic_n;
    #pragma unroll
    for (int m = 0; m < 4; m++) {
        gxr += dot4(WxR[l + 64*m], h4[m]);
        gxz += dot4(WxZ[l + 64*m], h4[m]);
        gxn += dot4(WxN[l + 64*m], h4[m]);
    }
    float4 xv[4];
    {
        int tok1 = __shfl(tokreg, 0);
        const float4* xp = (const float4*)(dec + (size_t)tok1 * EDIM);
        #pragma unroll
        for (int m = 0; m < 4; m++) xv[m] = xp[l + 64*m];
    }

    // h[j] extraction constants (wave-uniform)
    const int jmi = jr >> 8, jli = (jr >> 2) & 63, jci = jr & 3;

    for (int t = 0; t < 65; t++) {
        float hr = 0.f, hz = 0.f, hn_ = 0.f;
        #pragma unroll
        for (int m = 0; m < 4; m++) {
            hr  += dot4(whr[m], h4[m]);
            hz  += dot4(whz[m], h4[m]);
            hn_ += dot4(whn[m], h4[m]);
        }
        float sr = gxr + hr, sz = gxz + hz, sni = gxn, snh = hn_;
        #pragma unroll
        for (int off = 32; off; off >>= 1) {
            sr  += __shfl_xor(sr, off);  sz  += __shfl_xor(sz, off);
            sni += __shfl_xor(sni, off); snh += __shfl_xor(snh, off);
        }
        float rg = 1.f / (1.f + expf(-(sr + b_r)));
        float zg = 1.f / (1.f + expf(-(sz + b_z)));
        float ng = tanhf(sni + b_ni + rg * (snh + b_nh));

        float4 hs = (jmi == 0) ? h4[0] : (jmi == 1) ? h4[1] : (jmi == 2) ? h4[2] : h4[3];
        float hv0 = (jci == 0) ? hs.x : (jci == 1) ? hs.y : (jci == 2) ? hs.z : hs.w;
        float hv = __shfl(hv0, jli);
        float hnew = (1.f - zg) * ng + zg * hv;

        if (t < 64) {
            const int par = (t + 1) & 1;
            const unsigned tag = (unsigned)(t + 1);
            if (l == 0) {
                hrelu[t * 1024 + jr] = fmaxf(hnew, 0.f);
                u64 pk = ((u64)tag << 32) | (u64)__float_as_uint(hnew);
                #pragma unroll
                for (int x = 0; x < 8; x++)
                    __hip_atomic_store(&hbuf[x * 2048 + par * 1024 + jr], pk,
                                       __ATOMIC_RELAXED, __HIP_MEMORY_SCOPE_AGENT);
            }

            // ---- overlap: gx(t+1) + x prefetch while stores fly ----
            gxr = gic_r; gxz = gic_z; gxn = gic_n;
            #pragma unroll
            for (int m = 0; m < 4; m++) {
                gxr += dot4(WxR[l + 64*m], xv[m]);
                gxz += dot4(WxZ[l + 64*m], xv[m]);
                gxn += dot4(WxN[l + 64*m], xv[m]);
            }
            if (t < 63) {
                int tok = __shfl(tokreg, t + 1);
                const float4* xp = (const float4*)(dec + (size_t)tok * EDIM);
                #pragma unroll
                for (int m = 0; m < 4; m++) xv[m] = xp[l + 64*m];
            }

            // ---- poll own 2 slots of OWN XCD's replica ----
            {
                u64* hb = hbuf + xcc * 2048 + par * 1024;
                u64 va, vb2;
                while (1) {
                    va  = __hip_atomic_load(&hb[2*tid],     __ATOMIC_RELAXED, __HIP_MEMORY_SCOPE_AGENT);
                    vb2 = __hip_atomic_load(&hb[2*tid + 1], __ATOMIC_RELAXED, __HIP_MEMORY_SCOPE_AGENT);
                    if (((unsigned)(va >> 32) == tag) & ((unsigned)(vb2 >> 32) == tag)) break;
                }
                hlds[2*tid]     = __uint_as_float((unsigned)va);
                hlds[2*tid + 1] = __uint_as_float((unsigned)vb2);
            }
            __syncthreads();
            #pragma unroll
            for (int m = 0; m < 4; m++) h4[m] = ((const float4*)hlds)[l + 64*m];
            __syncthreads();
        } else {
            if (l == 0) hrelu[64 * 1024 + jr] = fmaxf(hnew, 0.f);
        }
    }
}

// ---------------------------------------------------------------------------
// logits = out_w @ relu(H)^T + out_b.
// Block 256 thr, tile 16 v x 65 t. Thread (q=tid&15, vl=(tid>>4)&3, s=tid>>6):
// rows {v0+vl+4r, r<4}, t in [16s,16s+16) -- UNIFORM acc[4][16], all static;
// t=64 handled by wave 0 via separate acc64[4] (predicated, static). R7's
// spill (VGPR=64, 2.7GB scratch) came from the 128-reg launch_bounds cap;
// (256,2) caps at 256 regs -> ~150 used, no spill, ~3 blocks/CU by VGPR.
// One 16B LDS read feeds 16 FMAs; LDS reads/thread/kc: 65 (R6) -> 17.
// ---------------------------------------------------------------------------
__global__ __launch_bounds__(256, 2) void k_logits(
    const float* __restrict__ wo, const float* __restrict__ bo,
    const float* __restrict__ hrelu, float* __restrict__ out)
{
    __shared__ float Hs[65 * 68];     // 17.7KB; reused as Os[65][17] at the end
    const int tid = threadIdx.x;
    const int q = tid & 15, vl = (tid >> 4) & 3, s = tid >> 6;
    const int v0 = blockIdx.x * 16;

    const float* wrow[4];
    #pragma unroll
    for (int r = 0; r < 4; r++) {
        int v = v0 + vl + 4*r;
        wrow[r] = wo + (size_t)((v < 32002) ? v : 32001) * 1024;
    }

    float acc[4][16];
    #pragma unroll
    for (int r = 0; r < 4; r++)
        #pragma unroll
        for (int ti = 0; ti < 16; ti++) acc[r][ti] = 0.f;
    float acc64[4];
    #pragma unroll
    for (int r = 0; r < 4; r++) acc64[r] = 0.f;

    // stage registers: 4 float4/thread + 1 extra for tid<16 (65*16 = 1040)
    float4 st0, st1, st2, st3, st4;
    #define ISSUE(kc_) do {                                                   \
        int base = (kc_) * 64;                                                \
        { int idx = tid;       st0 = *(const float4*)(hrelu + (idx>>4)*1024 + base + 4*(idx&15)); } \
        { int idx = tid + 256; st1 = *(const float4*)(hrelu + (idx>>4)*1024 + base + 4*(idx&15)); } \
        { int idx = tid + 512; st2 = *(const float4*)(hrelu + (idx>>4)*1024 + base + 4*(idx&15)); } \
        { int idx = tid + 768; st3 = *(const float4*)(hrelu + (idx>>4)*1024 + base + 4*(idx&15)); } \
        if (tid < 16) st4 = *(const float4*)(hrelu + 64*1024 + base + 4*tid); \
    } while (0)
    #define WRITE() do {                                                      \
        { int idx = tid;       *(float4*)(Hs + (idx>>4)*68 + 4*(idx&15)) = st0; } \
        { int idx = tid + 256; *(float4*)(Hs + (idx>>4)*68 + 4*(idx&15)) = st1; } \
        { int idx = tid + 512; *(float4*)(Hs + (idx>>4)*68 + 4*(idx&15)) = st2; } \
        { int idx = tid + 768; *(float4*)(Hs + (idx>>4)*68 + 4*(idx&15)) = st3; } \
        if (tid < 16) *(float4*)(Hs + 64*68 + 4*tid) = st4;                   \
    } while (0)

    ISSUE(0);

    for (int kc = 0; kc < 16; kc++) {
        WRITE();                       // consumes stage regs of kc
        __syncthreads();               // Hs(kc) ready
        if (kc < 15) ISSUE(kc + 1);    // next tile in flight during compute

        float4 wv[4];
        #pragma unroll
        for (int r = 0; r < 4; r++) wv[r] = *(const float4*)(wrow[r] + kc * 64 + 4*q);

        const float* hp = Hs + 4*q;
        #pragma unroll
        for (int ti = 0; ti < 16; ti++) {
            float4 h4 = *(const float4*)(hp + (16*s + ti) * 68);
            #pragma unroll
            for (int r = 0; r < 4; r++) {
                acc[r][ti] = fmaf(wv[r].x, h4.x, acc[r][ti]);
                acc[r][ti] = fmaf(wv[r].y, h4.y, acc[r][ti]);
                acc[r][ti] = fmaf(wv[r].z, h4.z, acc[r][ti]);
                acc[r][ti] = fmaf(wv[r].w, h4.w, acc[r][ti]);
            }
        }
        if (s == 0) {                  // wave 0 also covers t=64 (wave-uniform)
            float4 h4 = *(const float4*)(hp + 64 * 68);
            #pragma unroll
            for (int r = 0; r < 4; r++) {
                acc64[r] = fmaf(wv[r].x, h4.x, acc64[r]);
                acc64[r] = fmaf(wv[r].y, h4.y, acc64[r]);
                acc64[r] = fmaf(wv[r].z, h4.z, acc64[r]);
                acc64[r] = fmaf(wv[r].w, h4.w, acc64[r]);
            }
        }
        __syncthreads();               // Hs consumed; next WRITE may proceed
    }

    // reduce over q (16-lane groups), stage Os[65][17], coalesced store
    float* Os = Hs;
    #pragma unroll
    for (int ti = 0; ti < 16; ti++) {
        #pragma unroll
        for (int r = 0; r < 4; r++) {
            float s_ = acc[r][ti];
            s_ += __shfl_xor(s_, 1);
            s_ += __shfl_xor(s_, 2);
            s_ += __shfl_xor(s_, 4);
            s_ += __shfl_xor(s_, 8);
            if (q == 0) Os[(16*s + ti) * 17 + vl + 4*r] = s_;
        }
    }
    if (s == 0) {
        #pragma unroll
        for (int r = 0; r < 4; r++) {
            float s_ = acc64[r];
            s_ += __shfl_xor(s_, 1);
            s_ += __shfl_xor(s_, 2);
            s_ += __shfl_xor(s_, 4);
            s_ += __shfl_xor(s_, 8);
            if (q == 0) Os[64 * 17 + vl + 4*r] = s_;
        }
    }
    __syncthreads();
    for (int idx = tid; idx < 65 * 16; idx += 256) {
        int t = idx >> 4, c = idx & 15;
        int vv = v0 + c;
        if (vv < 32002) out[(size_t)t * 32002 + vv] = Os[t * 17 + c] + bo[vv];
    }
}

// ---------------------------------------------------------------------------
extern "C" void kernel_launch(void* const* d_in, const int* in_sizes, int n_in,
                              void* d_out, int out_size, void* d_ws, size_t ws_size,
                              hipStream_t stream) {
    const int*   diag = (const int*)d_in[0];
    const int*   proc = (const int*)d_in[1];
    const int*   med  = (const int*)d_in[2];
    const int*   dtok = (const int*)d_in[3];
    const float* enc  = (const float*)d_in[4];
    const float* dec  = (const float*)d_in[5];
    const float* attw = (const float*)d_in[6];
    // d_in[7] = attn_b: uniform shift, cancels in softmax -> unused
    const float* wih  = (const float*)d_in[8];
    const float* whh  = (const float*)d_in[9];
    const float* bih  = (const float*)d_in[10];
    const float* bhh  = (const float*)d_in[11];
    const float* wo   = (const float*)d_in[12];
    const float* bo   = (const float*)d_in[13];
    float* out = (float*)d_out;

    // ws: [0,1280) ctx | [2048,6144) c | [16384,147456) hbuf[8 xcd][2 par][1024] u64 |
    //     [147456,413696) hrelu
    float* ctx_ws = (float*)d_ws;
    float* c_ws   = (float*)((char*)d_ws + 2048);
    u64*   hbuf   = (u64*)  ((char*)d_ws + 16384);
    float* hrelu  = (float*)((char*)d_ws + 147456);

    void* args[] = { (void*)&diag, (void*)&proc, (void*)&med, (void*)&dtok,
                     (void*)&enc, (void*)&dec, (void*)&attw,
                     (void*)&wih, (void*)&whh, (void*)&bih, (void*)&bhh,
                     (void*)&ctx_ws, (void*)&c_ws, (void*)&hbuf, (void*)&hrelu };
    hipLaunchCooperativeKernel((void*)k_rnn, dim3(128), dim3(512), args, 0, stream);

    k_logits<<<dim3(2001), dim3(256), 0, stream>>>(wo, bo, hrelu, out);
}